// Round 10
// baseline (380.941 us; speedup 1.0000x reference)
//
#include <hip/hip_runtime.h>
#include <hip/hip_bf16.h>

// C2QAttention: softmax(sim[B,C,Q], axis=Q) @ enc[B,Q,D] -> out[B,C,D]
// B=32, C=4096, Q=512, D=512. fp32 in/out; bf16 MFMA, deferred normalization.
// Round 10 = Round 7 structure (64-row panel, BK=64 K-pipeline, dbuf LDS
// A-tile, fragment-major L2-resident Etf, b-pinned XCD grid) with:
//  (1) NON-DRAINING barriers (lgkmcnt(0) + raw s_barrier; vmcnt stays open so
//      sim prefetch / B-refills / stores genuinely cross steps),
//  (2) persistent blocks: 256 blocks x 8 panels; next panel's loads are issued
//      BEFORE this panel's stores (in-order vmcnt -> stores drain in background
//      under the next panel's compute).

constexpr int Bn = 32;
constexpr int Cn = 4096;
constexpr int Qn = 512;
constexpr int Dn = 512;

typedef __attribute__((ext_vector_type(8))) short short8;
typedef __attribute__((ext_vector_type(4))) float floatx4;

__device__ __forceinline__ ushort f2bf(float f) {
  union { float f; unsigned u; } v; v.f = f;
  unsigned r = v.u + 0x7FFFu + ((v.u >> 16) & 1u);   // RNE
  return (ushort)(r >> 16);
}

__device__ __forceinline__ uint4 exp_pack(float4 x, float4 y, float& rsum) {
  float e0 = __expf(x.x), e1 = __expf(x.y), e2 = __expf(x.z), e3 = __expf(x.w);
  float e4 = __expf(y.x), e5 = __expf(y.y), e6 = __expf(y.z), e7 = __expf(y.w);
  rsum += ((e0 + e1) + (e2 + e3)) + ((e4 + e5) + (e6 + e7));
  uint4 pk;
  pk.x = (uint)f2bf(e0) | ((uint)f2bf(e1) << 16);
  pk.y = (uint)f2bf(e2) | ((uint)f2bf(e3) << 16);
  pk.z = (uint)f2bf(e4) | ((uint)f2bf(e5) << 16);
  pk.w = (uint)f2bf(e6) | ((uint)f2bf(e7) << 16);
  return pk;
}

// Non-draining workgroup barrier: producer LDS writes flushed (lgkmcnt(0)),
// vmcnt left open so global loads/stores stay in flight across the barrier.
#define BARRIER_NODRAIN() do {                                   \
  __builtin_amdgcn_sched_barrier(0);                             \
  asm volatile("s_waitcnt lgkmcnt(0)" ::: "memory");             \
  __builtin_amdgcn_s_barrier();                                  \
  asm volatile("" ::: "memory");                                 \
  __builtin_amdgcn_sched_barrier(0);                             \
} while (0)

// enc[b][q][d] f32 -> Etf fragment-major: [b][dtile(32)][kidx(16)][lane(64)]x16B
// chunk(b,dt,kidx): lane=lhi*16+l16 holds bf16[j]=enc[b][kidx*32+lhi*8+j][dt*16+l16]
__global__ __launch_bounds__(256) void enc_to_frag(const float* __restrict__ E,
                                                   ushort* __restrict__ Etf) {
  const int ks = blockIdx.x, b = blockIdx.y;
  const int t = threadIdx.x;
  const int lane = t & 63, grp = t >> 6;
  const int l16 = lane & 15, lhi = lane >> 4;
  const float* src = E + ((size_t)b * Qn + ks * 32 + lhi * 8) * Dn + l16;
#pragma unroll
  for (int dt8 = 0; dt8 < 8; ++dt8) {
    int dt = grp * 8 + dt8;
    float e[8];
#pragma unroll
    for (int j = 0; j < 8; ++j) e[j] = src[(size_t)j * Dn + dt * 16];
    uint4 pk;
    pk.x = (uint)f2bf(e[0]) | ((uint)f2bf(e[1]) << 16);
    pk.y = (uint)f2bf(e[2]) | ((uint)f2bf(e[3]) << 16);
    pk.z = (uint)f2bf(e[4]) | ((uint)f2bf(e[5]) << 16);
    pk.w = (uint)f2bf(e[6]) | ((uint)f2bf(e[7]) << 16);
    *(uint4*)((char*)Etf + (((size_t)(b * 32 + dt) * 16 + ks) * 64 + lane) * 16) = pk;
  }
}

__global__ __launch_bounds__(512, 2) void c2q_fused(const float* __restrict__ sim,
                                                    const ushort* __restrict__ Etf,
                                                    float* __restrict__ out) {
  __shared__ char Abuf[2][64 * 128];   // [buf][row*128B] bf16, XOR-swizzled
  __shared__ float rsInv[64];

  const int tid  = threadIdx.x;
  const int lane = tid & 63;
  const int wid  = tid >> 6;           // 0..7 -> 64 D-cols each
  const int l16  = lane & 15;
  const int lhi  = lane >> 4;          // 0..3

  // 256 persistent blocks: XCD = lin&7 -> 4 distinct b per XCD (Et 2MB/L2);
  // g selects the 512-row group; 8 panels of 64 rows walked sequentially.
  const int lin = blockIdx.x;          // 0..255
  const int blo = lin & 7;
  const int bhi = (lin >> 3) & 3;
  const int g   = lin >> 5;            // 0..7
  const int b   = bhi * 8 + blo;

  // staging: thread owns (row srow, k-octet so): 8 floats per step
  const int srow = tid >> 3;           // 0..63
  const int so   = tid & 7;            // 0..7
  const float* sload = sim + ((size_t)b * Cn + g * 512 + srow) * Qn + so * 8;
  float*       outp  = out + ((size_t)b * Cn + g * 512) * Dn + wid * 64;
  const int swa = (srow * 128 + so * 16) ^ ((srow & 7) << 4);

  // B-frag base: chunk (b, dt = wid*4 + nr, kidx), this lane's 16B
  const short8* EB = (const short8*)Etf + ((size_t)(b * 32 + wid * 4) * 16) * 64 + lane;

  float4 vs[2][2];                     // sim 2-step-ahead double buffer
  short8 bfr[2][4];                    // B-frag 2-deep rotate

  // ---- pre-issue panel 0 prologue loads ----
  vs[0][0] = *(const float4*)(sload);
  vs[0][1] = *(const float4*)(sload + 4);
  vs[1][0] = *(const float4*)(sload + 64);
  vs[1][1] = *(const float4*)(sload + 68);
#pragma unroll
  for (int nr = 0; nr < 4; ++nr) {
    bfr[0][nr] = EB[((size_t)nr * 16) * 64];
    bfr[1][nr] = EB[((size_t)nr * 16 + 1) * 64];
  }

#pragma unroll 1
  for (int p = 0; p < 8; ++p) {
    float rsum = 0.0f;
    floatx4 acc[4][4] = {};

    // prologue: stage data(0)
    *(uint4*)(Abuf[0] + swa) = exp_pack(vs[0][0], vs[0][1], rsum);
    BARRIER_NODRAIN();

#pragma unroll
    for (int t = 0; t < 8; ++t) {
      // (a) issue sim loads for step t+2
      if (t < 6) {
        vs[t & 1][0] = *(const float4*)(sload + (t + 2) * 64);
        vs[t & 1][1] = *(const float4*)(sload + (t + 2) * 64 + 4);
      }
      __builtin_amdgcn_sched_barrier(0);

      // (b) MFMA on Abuf[t&1], 2 k-slices of 32
#pragma unroll
      for (int ks = 0; ks < 2; ++ks) {
        const int kidx = 2 * t + ks;
        short8 a[4];
#pragma unroll
        for (int mr = 0; mr < 4; ++mr) {
          int row = mr * 16 + l16;
          a[mr] = *(const short8*)(Abuf[t & 1] +
                   ((row * 128 + ks * 64 + lhi * 16) ^ ((row & 7) << 4)));
        }
        __builtin_amdgcn_s_setprio(1);
#pragma unroll
        for (int mr = 0; mr < 4; ++mr)
#pragma unroll
          for (int nr = 0; nr < 4; ++nr)
            acc[mr][nr] = __builtin_amdgcn_mfma_f32_16x16x32_bf16(
                a[mr], bfr[kidx & 1][nr], acc[mr][nr], 0, 0, 0);
        __builtin_amdgcn_s_setprio(0);
        // refill just-consumed B slot with kidx+2 (2-deep, L2-resident)
        if (kidx < 14) {
#pragma unroll
          for (int nr = 0; nr < 4; ++nr)
            bfr[kidx & 1][nr] = EB[((size_t)nr * 16 + kidx + 2) * 64];
        }
      }

      // (c) stage data(t+1); last step: finalize rowsums
      if (t < 7) {
        *(uint4*)(Abuf[(t + 1) & 1] + swa) =
            exp_pack(vs[(t + 1) & 1][0], vs[(t + 1) & 1][1], rsum);
      } else {
        rsum += __shfl_xor(rsum, 1);
        rsum += __shfl_xor(rsum, 2);
        rsum += __shfl_xor(rsum, 4);
        if (so == 0) rsInv[srow] = 1.0f / rsum;
      }
      BARRIER_NODRAIN();
    }

    // pre-issue NEXT panel's prologue loads BEFORE this panel's stores
    // (in-order vmcnt: waiting on these loads later won't drain the stores)
    if (p < 7) {
      const float* nsl = sload + (size_t)64 * Qn;
      vs[0][0] = *(const float4*)(nsl);
      vs[0][1] = *(const float4*)(nsl + 4);
      vs[1][0] = *(const float4*)(nsl + 64);
      vs[1][1] = *(const float4*)(nsl + 68);
#pragma unroll
      for (int nr = 0; nr < 4; ++nr) {
        bfr[0][nr] = EB[((size_t)nr * 16) * 64];
        bfr[1][nr] = EB[((size_t)nr * 16 + 1) * 64];
      }
    }
    __builtin_amdgcn_sched_barrier(0);

    // epilogue: scale by 1/rowsum, store (drains in background)
#pragma unroll
    for (int mr = 0; mr < 4; ++mr) {
      float rs[4];
#pragma unroll
      for (int rr = 0; rr < 4; ++rr) rs[rr] = rsInv[mr * 16 + lhi * 4 + rr];
#pragma unroll
      for (int nr = 0; nr < 4; ++nr) {
#pragma unroll
        for (int rr = 0; rr < 4; ++rr) {
          int row = mr * 16 + lhi * 4 + rr;
          outp[(size_t)row * Dn + nr * 16 + l16] = acc[mr][nr][rr] * rs[rr];
        }
      }
    }

    sload += (size_t)64 * Qn;
    outp  += (size_t)64 * Dn;
  }
}

extern "C" void kernel_launch(void* const* d_in, const int* in_sizes, int n_in,
                              void* d_out, int out_size, void* d_ws, size_t ws_size,
                              hipStream_t stream) {
  const float* sim = (const float*)d_in[0];
  const float* enc = (const float*)d_in[1];
  float* outp = (float*)d_out;
  ushort* Etf = (ushort*)d_ws;  // 32*32*16*64*16 B = 16.8 MB

  enc_to_frag<<<dim3(16, Bn), 256, 0, stream>>>(enc, Etf);
  c2q_fused<<<dim3(256), 512, 0, stream>>>(sim, Etf, outp);
}

// Round 11
// 166.705 us; speedup vs baseline: 2.2851x; 2.2851x over previous
//
#include <hip/hip_runtime.h>
#include <hip/hip_bf16.h>

// C2QAttention: softmax(sim[B,C,Q], axis=Q) @ enc[B,Q,D] -> out[B,C,D]
// B=32, C=4096, Q=512, D=512. fp32 in/out; bf16 MFMA, deferred normalization.
// Round 11 = EXACT Round 7 (165.6 us: 64-row block, BK=64 K-pipeline, dbuf LDS
// A-tile, 2-deep sim prefetch, 2-deep B-frag rotate from L2-resident Etf,
// b-pinned XCD grid) with ONE change: __syncthreads() -> BARRIER_NODRAIN
// (lgkmcnt(0) + raw s_barrier; vmcnt left open so the 2-step-ahead sim
// prefetch and B-refills actually survive the barrier instead of draining).

constexpr int Bn = 32;
constexpr int Cn = 4096;
constexpr int Qn = 512;
constexpr int Dn = 512;

typedef __attribute__((ext_vector_type(8))) short short8;
typedef __attribute__((ext_vector_type(4))) float floatx4;

__device__ __forceinline__ ushort f2bf(float f) {
  union { float f; unsigned u; } v; v.f = f;
  unsigned r = v.u + 0x7FFFu + ((v.u >> 16) & 1u);   // RNE
  return (ushort)(r >> 16);
}

__device__ __forceinline__ uint4 exp_pack(float4 x, float4 y, float& rsum) {
  float e0 = __expf(x.x), e1 = __expf(x.y), e2 = __expf(x.z), e3 = __expf(x.w);
  float e4 = __expf(y.x), e5 = __expf(y.y), e6 = __expf(y.z), e7 = __expf(y.w);
  rsum += ((e0 + e1) + (e2 + e3)) + ((e4 + e5) + (e6 + e7));
  uint4 pk;
  pk.x = (uint)f2bf(e0) | ((uint)f2bf(e1) << 16);
  pk.y = (uint)f2bf(e2) | ((uint)f2bf(e3) << 16);
  pk.z = (uint)f2bf(e4) | ((uint)f2bf(e5) << 16);
  pk.w = (uint)f2bf(e6) | ((uint)f2bf(e7) << 16);
  return pk;
}

// Non-draining workgroup barrier: producer LDS writes flushed (lgkmcnt(0)),
// vmcnt left open so global loads stay in flight across the barrier.
// Compiler still inserts vmcnt(N) waits at register-use sites.
#define BARRIER_NODRAIN() do {                                   \
  __builtin_amdgcn_sched_barrier(0);                             \
  asm volatile("s_waitcnt lgkmcnt(0)" ::: "memory");             \
  __builtin_amdgcn_s_barrier();                                  \
  asm volatile("" ::: "memory");                                 \
  __builtin_amdgcn_sched_barrier(0);                             \
} while (0)

// enc[b][q][d] f32 -> Etf fragment-major: [b][dtile(32)][kidx(16)][lane(64)]x16B
// chunk(b,dt,kidx): lane=lhi*16+l16 holds bf16[j]=enc[b][kidx*32+lhi*8+j][dt*16+l16]
__global__ __launch_bounds__(256) void enc_to_frag(const float* __restrict__ E,
                                                   ushort* __restrict__ Etf) {
  const int ks = blockIdx.x, b = blockIdx.y;
  const int t = threadIdx.x;
  const int lane = t & 63, grp = t >> 6;
  const int l16 = lane & 15, lhi = lane >> 4;
  const float* src = E + ((size_t)b * Qn + ks * 32 + lhi * 8) * Dn + l16;
#pragma unroll
  for (int dt8 = 0; dt8 < 8; ++dt8) {
    int dt = grp * 8 + dt8;
    float e[8];
#pragma unroll
    for (int j = 0; j < 8; ++j) e[j] = src[(size_t)j * Dn + dt * 16];
    uint4 pk;
    pk.x = (uint)f2bf(e[0]) | ((uint)f2bf(e[1]) << 16);
    pk.y = (uint)f2bf(e[2]) | ((uint)f2bf(e[3]) << 16);
    pk.z = (uint)f2bf(e[4]) | ((uint)f2bf(e[5]) << 16);
    pk.w = (uint)f2bf(e[6]) | ((uint)f2bf(e[7]) << 16);
    *(uint4*)((char*)Etf + (((size_t)(b * 32 + dt) * 16 + ks) * 64 + lane) * 16) = pk;
  }
}

__global__ __launch_bounds__(512, 2) void c2q_fused(const float* __restrict__ sim,
                                                    const ushort* __restrict__ Etf,
                                                    float* __restrict__ out) {
  __shared__ char Abuf[2][64 * 128];   // [buf][row*128B] bf16, XOR-swizzled
  __shared__ float rsInv[64];

  const int tid  = threadIdx.x;
  const int lane = tid & 63;
  const int wid  = tid >> 6;           // 0..7 -> 64 D-cols each
  const int l16  = lane & 15;
  const int lhi  = lane >> 4;          // 0..3

  // b-pinned XCD grid: XCD = lin&7 -> 4 b per XCD, Et 2MB per XCD L2
  const int lin = blockIdx.x;          // 2048 = 64 mtiles x 32 b
  const int blo = lin & 7;
  const int bhi = (lin >> 3) & 3;
  const int mt  = lin >> 5;
  const int b   = bhi * 8 + blo;
  const int c0  = mt * 64;

  // staging: thread owns (row srow, k-octet so): 8 floats per step
  const int srow = tid >> 3;           // 0..63
  const int so   = tid & 7;            // 0..7
  const float* sload = sim + ((size_t)b * Cn + c0 + srow) * Qn + so * 8;
  const int swa = (srow * 128 + so * 16) ^ ((srow & 7) << 4);

  // B-frag base: chunk (b, dt = wid*4 + nr, kidx), this lane's 16B
  const short8* EB = (const short8*)Etf + ((size_t)(b * 32 + wid * 4) * 16) * 64 + lane;

  float rsum = 0.0f;
  floatx4 acc[4][4] = {};
  float4 vs[2][2];                     // 2 slots x 2 float4 (static-indexed)
  short8 bfr[2][4];                    // B-frag 2-deep rotate

  // ---- prologue: data(0) -> Abuf[0]; data(1) -> slot1; B kidx 0,1 ----
  vs[0][0] = *(const float4*)(sload);
  vs[0][1] = *(const float4*)(sload + 4);
  vs[1][0] = *(const float4*)(sload + 64);
  vs[1][1] = *(const float4*)(sload + 68);
#pragma unroll
  for (int nr = 0; nr < 4; ++nr) {
    bfr[0][nr] = EB[((size_t)nr * 16 + 0) * 64];
    bfr[1][nr] = EB[((size_t)nr * 16 + 1) * 64];
  }
  *(uint4*)(Abuf[0] + swa) = exp_pack(vs[0][0], vs[0][1], rsum);
  BARRIER_NODRAIN();

#pragma unroll
  for (int t = 0; t < 8; ++t) {
    // (a) issue sim loads for step t+2 into the slot freed at step t-1
    if (t < 6) {
      vs[t & 1][0] = *(const float4*)(sload + (t + 2) * 64);
      vs[t & 1][1] = *(const float4*)(sload + (t + 2) * 64 + 4);
    }
    __builtin_amdgcn_sched_barrier(0);

    // (b) MFMA on Abuf[t&1], 2 k-slices of 32
#pragma unroll
    for (int ks = 0; ks < 2; ++ks) {
      const int kidx = 2 * t + ks;
      short8 a[4];
#pragma unroll
      for (int mr = 0; mr < 4; ++mr) {
        int row = mr * 16 + l16;
        a[mr] = *(const short8*)(Abuf[t & 1] +
                 ((row * 128 + ks * 64 + lhi * 16) ^ ((row & 7) << 4)));
      }
      __builtin_amdgcn_s_setprio(1);
#pragma unroll
      for (int mr = 0; mr < 4; ++mr)
#pragma unroll
        for (int nr = 0; nr < 4; ++nr)
          acc[mr][nr] = __builtin_amdgcn_mfma_f32_16x16x32_bf16(
              a[mr], bfr[kidx & 1][nr], acc[mr][nr], 0, 0, 0);
      __builtin_amdgcn_s_setprio(0);
      // refill just-consumed B slot with kidx+2 (2-deep, L2-resident)
      if (kidx < 14) {
#pragma unroll
        for (int nr = 0; nr < 4; ++nr)
          bfr[kidx & 1][nr] = EB[((size_t)nr * 16 + kidx + 2) * 64];
      }
    }

    // (c) exp + stage data(t+1) into Abuf[(t+1)&1]; last step: finalize rowsum
    if (t < 7) {
      *(uint4*)(Abuf[(t + 1) & 1] + swa) =
          exp_pack(vs[(t + 1) & 1][0], vs[(t + 1) & 1][1], rsum);
    } else {
      rsum += __shfl_xor(rsum, 1);
      rsum += __shfl_xor(rsum, 2);
      rsum += __shfl_xor(rsum, 4);
      if (so == 0) rsInv[srow] = 1.0f / rsum;
    }
    BARRIER_NODRAIN();
  }

  // ---- epilogue: scale by 1/rowsum, store ----
  float* outp = out + ((size_t)b * Cn + c0) * Dn + wid * 64;
#pragma unroll
  for (int mr = 0; mr < 4; ++mr) {
    float rs[4];
#pragma unroll
    for (int rr = 0; rr < 4; ++rr) rs[rr] = rsInv[mr * 16 + lhi * 4 + rr];
#pragma unroll
    for (int nr = 0; nr < 4; ++nr) {
#pragma unroll
      for (int rr = 0; rr < 4; ++rr) {
        int row = mr * 16 + lhi * 4 + rr;
        outp[(size_t)row * Dn + nr * 16 + l16] = acc[mr][nr][rr] * rs[rr];
      }
    }
  }
}

extern "C" void kernel_launch(void* const* d_in, const int* in_sizes, int n_in,
                              void* d_out, int out_size, void* d_ws, size_t ws_size,
                              hipStream_t stream) {
  const float* sim = (const float*)d_in[0];
  const float* enc = (const float*)d_in[1];
  float* outp = (float*)d_out;
  ushort* Etf = (ushort*)d_ws;  // 32*32*16*64*16 B = 16.8 MB

  enc_to_frag<<<dim3(16, Bn), 256, 0, stream>>>(enc, Etf);
  c2q_fused<<<dim3(2048), 512, 0, stream>>>(sim, Etf, outp);
}